// Round 1
// baseline (5470.466 us; speedup 1.0000x reference)
//
#include <hip/hip_runtime.h>
#include <math.h>

#define NN 50000
#define NE 1600000
#define KORD 5

// ---------------- preprocessing ----------------

__global__ __launch_bounds__(256) void k_deg(const int* __restrict__ ei,
                                             const float* __restrict__ ew,
                                             float* __restrict__ deg) {
    int e = blockIdx.x * 256 + threadIdx.x;
    if (e < NE) unsafeAtomicAdd(&deg[ei[e]], ew[e]);
}

__global__ __launch_bounds__(256) void k_dis(float* __restrict__ deg) {
    int n = blockIdx.x * 256 + threadIdx.x;
    if (n < NN) {
        float d = deg[n];
        deg[n] = d > 0.f ? rsqrtf(fmaxf(d, 1e-30f)) : 0.f;
    }
}

__global__ __launch_bounds__(256) void k_wn(const int* __restrict__ ei,
                                            const float* __restrict__ ew,
                                            const float* __restrict__ dis,
                                            float* __restrict__ wn) {
    int e = blockIdx.x * 256 + threadIdx.x;
    if (e < NE) {
        wn[e] = -dis[ei[e]] * ew[e] * dis[ei[NE + e]];
    }
}

// dst = -src (float4), used to fold "- Tx_{k-2}" into the scatter accumulator
__global__ __launch_bounds__(256) void k_neg(const float* __restrict__ src,
                                             float* __restrict__ dst, int n4) {
    int i = blockIdx.x * 256 + threadIdx.x;
    if (i < n4) {
        float4 v = ((const float4*)src)[i];
        ((float4*)dst)[i] = make_float4(-v.x, -v.y, -v.z, -v.w);
    }
}

// ---------------- spmm scatter: vout[c] += scale*wn[e]*vin[r], 32 features ----

__global__ __launch_bounds__(256) void k_scatter(const int* __restrict__ ei,
                                                 const float* __restrict__ wn,
                                                 const float* __restrict__ vin,
                                                 float* __restrict__ vout,
                                                 float scale) {
    int t = blockIdx.x * 256 + threadIdx.x;
    if (t >= NE * 8) return;
    int e = t >> 3;
    int f4 = (t & 7) << 2;
    int r = ei[e];
    int c = ei[NE + e];
    float w = wn[e] * scale;
    float4 v = *(const float4*)(vin + r * 32 + f4);
    float* o = vout + c * 32 + f4;
    unsafeAtomicAdd(o + 0, w * v.x);
    unsafeAtomicAdd(o + 1, w * v.y);
    unsafeAtomicAdd(o + 2, w * v.z);
    unsafeAtomicAdd(o + 3, w * v.w);
}

// ---------------- fused gate GEMM + GRU nonlinearity, cell 1 ----------------
// H=0 => h = relu((1 - sigmoid(sum_k Txk@Wx1[0,k] + bx1[0] + bh1[0]))
//              * tanh(sum_k Txk@Wx1[2,k] + bx1[2] + bh1[2]))

__global__ __launch_bounds__(256) void k_epi1(
    const float* __restrict__ x, const float* __restrict__ t1,
    const float* __restrict__ t2, const float* __restrict__ t3,
    const float* __restrict__ t4, const float* __restrict__ Wx1,
    const float* __restrict__ bx1, const float* __restrict__ bh1,
    float* __restrict__ h) {
    int n = blockIdx.x * 256 + threadIdx.x;
    if (n >= NN) return;
    const float* tp[KORD] = {x + n * 32, t1 + n * 32, t2 + n * 32,
                             t3 + n * 32, t4 + n * 32};
    float accz[32], acch[32];
#pragma unroll
    for (int j = 0; j < 32; j++) { accz[j] = 0.f; acch[j] = 0.f; }
    const float* Wz = Wx1;                      // gate 0
    const float* Wh = Wx1 + 2 * KORD * 32 * 32; // gate 2
#pragma unroll
    for (int k = 0; k < KORD; k++) {
        const float* txp = tp[k];
        const float* wz = Wz + k * 32 * 32;
        const float* wh = Wh + k * 32 * 32;
        for (int i = 0; i < 32; i++) {
            float tx = txp[i];
#pragma unroll
            for (int j = 0; j < 32; j++) {
                accz[j] = fmaf(tx, wz[i * 32 + j], accz[j]);
                acch[j] = fmaf(tx, wh[i * 32 + j], acch[j]);
            }
        }
    }
#pragma unroll
    for (int j = 0; j < 32; j++) {
        float az = accz[j] + bx1[j] + bh1[j];
        float ah = acch[j] + bx1[64 + j] + bh1[64 + j];
        float z = 1.f / (1.f + __expf(-az));
        float t = __expf(-2.f * fabsf(ah));
        float ht = copysignf((1.f - t) / (1.f + t), ah);
        float v = (1.f - z) * ht;
        h[n * 32 + j] = fmaxf(v, 0.f);
    }
}

// ---------------- cell 2 epilogue fused with final linear ----------------

__global__ __launch_bounds__(256) void k_epi2(
    const float* __restrict__ h, const float* __restrict__ t1,
    const float* __restrict__ t2, const float* __restrict__ t3,
    const float* __restrict__ t4, const float* __restrict__ Wx2,
    const float* __restrict__ bx2, const float* __restrict__ bh2,
    const float* __restrict__ Wl, const float* __restrict__ bl,
    float* __restrict__ out) {
    int n = blockIdx.x * 256 + threadIdx.x;
    if (n >= NN) return;
    const float* tp[KORD] = {h + n * 32, t1 + n * 32, t2 + n * 32,
                             t3 + n * 32, t4 + n * 32};
    float accz[16], acch[16];
#pragma unroll
    for (int j = 0; j < 16; j++) { accz[j] = 0.f; acch[j] = 0.f; }
    const float* Wz = Wx2;                      // [K][32][16], gate 0
    const float* Wh = Wx2 + 2 * KORD * 32 * 16; // gate 2
#pragma unroll
    for (int k = 0; k < KORD; k++) {
        const float* txp = tp[k];
        const float* wz = Wz + k * 32 * 16;
        const float* wh = Wh + k * 32 * 16;
        for (int i = 0; i < 32; i++) {
            float tx = txp[i];
#pragma unroll
            for (int j = 0; j < 16; j++) {
                accz[j] = fmaf(tx, wz[i * 16 + j], accz[j]);
                acch[j] = fmaf(tx, wh[i * 16 + j], acch[j]);
            }
        }
    }
    float h2[16];
#pragma unroll
    for (int j = 0; j < 16; j++) {
        float az = accz[j] + bx2[j] + bh2[j];
        float ah = acch[j] + bx2[32 + j] + bh2[32 + j];
        float z = 1.f / (1.f + __expf(-az));
        float t = __expf(-2.f * fabsf(ah));
        float ht = copysignf((1.f - t) / (1.f + t), ah);
        float v = (1.f - z) * ht;
        h2[j] = fmaxf(v, 0.f);
    }
#pragma unroll
    for (int p = 0; p < 12; p++) {
        float o = bl[p];
#pragma unroll
        for (int j = 0; j < 16; j++) o = fmaf(h2[j], Wl[p * 16 + j], o);
        out[n * 12 + p] = o;
    }
}

// ---------------- launch ----------------

extern "C" void kernel_launch(void* const* d_in, const int* in_sizes, int n_in,
                              void* d_out, int out_size, void* d_ws, size_t ws_size,
                              hipStream_t stream) {
    const float* x   = (const float*)d_in[0];
    const int*   ei  = (const int*)d_in[1];
    const float* ew  = (const float*)d_in[2];
    const float* Wx1 = (const float*)d_in[3];
    const float* bx1 = (const float*)d_in[4];
    const float* bh1 = (const float*)d_in[6];
    const float* Wx2 = (const float*)d_in[7];
    const float* bx2 = (const float*)d_in[8];
    const float* bh2 = (const float*)d_in[10];
    const float* Wl  = (const float*)d_in[11];
    const float* bl  = (const float*)d_in[12];
    float* out = (float*)d_out;

    float* ws  = (float*)d_ws;
    float* deg = ws;              // NN (becomes dis in-place)
    float* wn  = deg + 50048;     // NE
    float* T1  = wn + NE;         // NN*32 each
    float* T2  = T1 + NN * 32;
    float* T3  = T2 + NN * 32;
    float* T4  = T3 + NN * 32;
    float* hb  = T4 + NN * 32;

    const int gE = (NE + 255) / 256;
    const int gN = (NN + 255) / 256;
    const int n4 = NN * 32 / 4;
    const int gneg = (n4 + 255) / 256;
    const int gsc = (NE * 8 + 255) / 256;

    hipMemsetAsync(deg, 0, NN * sizeof(float), stream);
    k_deg<<<gE, 256, 0, stream>>>(ei, ew, deg);
    k_dis<<<gN, 256, 0, stream>>>(deg);
    k_wn<<<gE, 256, 0, stream>>>(ei, ew, deg, wn);

    // ---- cell 1: v = x ----
    hipMemsetAsync(T1, 0, NN * 32 * sizeof(float), stream);
    k_scatter<<<gsc, 256, 0, stream>>>(ei, wn, x, T1, 1.f);   // T1 = L x
    k_neg<<<gneg, 256, 0, stream>>>(x, T2, n4);
    k_scatter<<<gsc, 256, 0, stream>>>(ei, wn, T1, T2, 2.f);  // T2 = 2 L T1 - x
    k_neg<<<gneg, 256, 0, stream>>>(T1, T3, n4);
    k_scatter<<<gsc, 256, 0, stream>>>(ei, wn, T2, T3, 2.f);  // T3 = 2 L T2 - T1
    k_neg<<<gneg, 256, 0, stream>>>(T2, T4, n4);
    k_scatter<<<gsc, 256, 0, stream>>>(ei, wn, T3, T4, 2.f);  // T4 = 2 L T3 - T2
    k_epi1<<<gN, 256, 0, stream>>>(x, T1, T2, T3, T4, Wx1, bx1, bh1, hb);

    // ---- cell 2: v = hb (reuse T buffers) ----
    hipMemsetAsync(T1, 0, NN * 32 * sizeof(float), stream);
    k_scatter<<<gsc, 256, 0, stream>>>(ei, wn, hb, T1, 1.f);
    k_neg<<<gneg, 256, 0, stream>>>(hb, T2, n4);
    k_scatter<<<gsc, 256, 0, stream>>>(ei, wn, T1, T2, 2.f);
    k_neg<<<gneg, 256, 0, stream>>>(T1, T3, n4);
    k_scatter<<<gsc, 256, 0, stream>>>(ei, wn, T2, T3, 2.f);
    k_neg<<<gneg, 256, 0, stream>>>(T2, T4, n4);
    k_scatter<<<gsc, 256, 0, stream>>>(ei, wn, T3, T4, 2.f);
    k_epi2<<<gN, 256, 0, stream>>>(hb, T1, T2, T3, T4, Wx2, bx2, bh2, Wl, bl, out);
}

// Round 2
// 895.326 us; speedup vs baseline: 6.1100x; 6.1100x over previous
//
#include <hip/hip_runtime.h>
#include <math.h>

#define NN 50000
#define NE 1600000
#define KORD 5

// ---------------- preprocessing ----------------

__global__ __launch_bounds__(256) void k_deg(const int* __restrict__ ei,
                                             const float* __restrict__ ew,
                                             float* __restrict__ deg) {
    int e = blockIdx.x * 256 + threadIdx.x;
    if (e < NE) unsafeAtomicAdd(&deg[ei[e]], ew[e]);
}

__global__ __launch_bounds__(256) void k_dis(float* __restrict__ deg) {
    int n = blockIdx.x * 256 + threadIdx.x;
    if (n < NN) {
        float d = deg[n];
        deg[n] = d > 0.f ? rsqrtf(fmaxf(d, 1e-30f)) : 0.f;
    }
}

// histogram of destination (col) counts
__global__ __launch_bounds__(256) void k_hist(const int* __restrict__ ei,
                                              int* __restrict__ cnt) {
    int e = blockIdx.x * 256 + threadIdx.x;
    if (e < NE) atomicAdd(&cnt[ei[NE + e]], 1);
}

// single-block exclusive scan: off[0..NN] from cnt; cnt becomes the cursor copy
__global__ __launch_bounds__(1024) void k_scan(int* __restrict__ cnt,
                                               int* __restrict__ off) {
    __shared__ int partial[1024];
    const int CH = (NN + 1023) / 1024;  // 49
    int t = threadIdx.x;
    int base = t * CH;
    int s = 0;
    for (int i = 0; i < CH; i++) {
        int idx = base + i;
        if (idx < NN) s += cnt[idx];
    }
    partial[t] = s;
    __syncthreads();
    for (int d = 1; d < 1024; d <<= 1) {
        int v = (t >= d) ? partial[t - d] : 0;
        __syncthreads();
        partial[t] += v;
        __syncthreads();
    }
    int run = (t == 0) ? 0 : partial[t - 1];
    for (int i = 0; i < CH; i++) {
        int idx = base + i;
        if (idx < NN) {
            int c = cnt[idx];
            off[idx] = run;
            cnt[idx] = run;  // cursor for permute
            run += c;
        }
    }
    if (t == 1023) off[NN] = run;
}

// bucket edges by destination; pack (row, weight) into int2
__global__ __launch_bounds__(256) void k_permute(const int* __restrict__ ei,
                                                 const float* __restrict__ ew,
                                                 const float* __restrict__ dis,
                                                 int* __restrict__ cursor,
                                                 int2* __restrict__ edges) {
    int e = blockIdx.x * 256 + threadIdx.x;
    if (e >= NE) return;
    int r = ei[e], c = ei[NE + e];
    float w = -dis[r] * ew[e] * dis[c];
    int pos = atomicAdd(&cursor[c], 1);
    edges[pos] = make_int2(r, __float_as_int(w));
}

// ---------------- spmm gather: vout[n] = scale * sum_e w_e * vin[r_e] - prev[n]
// 8 lanes per node, float4 (4 features) per lane.

__global__ __launch_bounds__(256) void k_gather(const int* __restrict__ off,
                                                const int2* __restrict__ edges,
                                                const float* __restrict__ vin,
                                                const float* __restrict__ prev,
                                                float* __restrict__ vout,
                                                float scale) {
    int t = blockIdx.x * 256 + threadIdx.x;
    if (t >= NN * 8) return;
    int n = t >> 3, sub = t & 7;
    const float4* vin4 = (const float4*)vin;
    float4 acc = make_float4(0.f, 0.f, 0.f, 0.f);
    int e0 = off[n], e1 = off[n + 1];
    for (int i = e0; i < e1; i++) {
        int2 er = edges[i];
        float w = __int_as_float(er.y);
        float4 v = vin4[er.x * 8 + sub];
        acc.x = fmaf(w, v.x, acc.x);
        acc.y = fmaf(w, v.y, acc.y);
        acc.z = fmaf(w, v.z, acc.z);
        acc.w = fmaf(w, v.w, acc.w);
    }
    float4 o;
    if (prev) {
        float4 p = ((const float4*)prev)[t];
        o = make_float4(fmaf(scale, acc.x, -p.x), fmaf(scale, acc.y, -p.y),
                        fmaf(scale, acc.z, -p.z), fmaf(scale, acc.w, -p.w));
    } else {
        o = acc;
    }
    ((float4*)vout)[t] = o;
}

// ---------------- fused gate GEMM + GRU nonlinearity, cell 1 ----------------
// H=0 => h = relu((1 - sigmoid(sum_k Txk@Wx1[0,k] + bx1[0] + bh1[0]))
//              * tanh(sum_k Txk@Wx1[2,k] + bx1[2] + bh1[2]))

__global__ __launch_bounds__(256) void k_epi1(
    const float* __restrict__ x, const float* __restrict__ t1,
    const float* __restrict__ t2, const float* __restrict__ t3,
    const float* __restrict__ t4, const float* __restrict__ Wx1,
    const float* __restrict__ bx1, const float* __restrict__ bh1,
    float* __restrict__ h) {
    int n = blockIdx.x * 256 + threadIdx.x;
    if (n >= NN) return;
    const float* tp[KORD] = {x + n * 32, t1 + n * 32, t2 + n * 32,
                             t3 + n * 32, t4 + n * 32};
    float accz[32], acch[32];
#pragma unroll
    for (int j = 0; j < 32; j++) { accz[j] = 0.f; acch[j] = 0.f; }
    const float* Wz = Wx1;                      // gate 0
    const float* Wh = Wx1 + 2 * KORD * 32 * 32; // gate 2
#pragma unroll
    for (int k = 0; k < KORD; k++) {
        const float* txp = tp[k];
        const float* wz = Wz + k * 32 * 32;
        const float* wh = Wh + k * 32 * 32;
        for (int i = 0; i < 32; i++) {
            float tx = txp[i];
#pragma unroll
            for (int j = 0; j < 32; j++) {
                accz[j] = fmaf(tx, wz[i * 32 + j], accz[j]);
                acch[j] = fmaf(tx, wh[i * 32 + j], acch[j]);
            }
        }
    }
#pragma unroll
    for (int j = 0; j < 32; j++) {
        float az = accz[j] + bx1[j] + bh1[j];
        float ah = acch[j] + bx1[64 + j] + bh1[64 + j];
        float z = 1.f / (1.f + __expf(-az));
        float t = __expf(-2.f * fabsf(ah));
        float ht = copysignf((1.f - t) / (1.f + t), ah);
        float v = (1.f - z) * ht;
        h[n * 32 + j] = fmaxf(v, 0.f);
    }
}

// ---------------- cell 2 epilogue fused with final linear ----------------

__global__ __launch_bounds__(256) void k_epi2(
    const float* __restrict__ h, const float* __restrict__ t1,
    const float* __restrict__ t2, const float* __restrict__ t3,
    const float* __restrict__ t4, const float* __restrict__ Wx2,
    const float* __restrict__ bx2, const float* __restrict__ bh2,
    const float* __restrict__ Wl, const float* __restrict__ bl,
    float* __restrict__ out) {
    int n = blockIdx.x * 256 + threadIdx.x;
    if (n >= NN) return;
    const float* tp[KORD] = {h + n * 32, t1 + n * 32, t2 + n * 32,
                             t3 + n * 32, t4 + n * 32};
    float accz[16], acch[16];
#pragma unroll
    for (int j = 0; j < 16; j++) { accz[j] = 0.f; acch[j] = 0.f; }
    const float* Wz = Wx2;                      // [K][32][16], gate 0
    const float* Wh = Wx2 + 2 * KORD * 32 * 16; // gate 2
#pragma unroll
    for (int k = 0; k < KORD; k++) {
        const float* txp = tp[k];
        const float* wz = Wz + k * 32 * 16;
        const float* wh = Wh + k * 32 * 16;
        for (int i = 0; i < 32; i++) {
            float tx = txp[i];
#pragma unroll
            for (int j = 0; j < 16; j++) {
                accz[j] = fmaf(tx, wz[i * 16 + j], accz[j]);
                acch[j] = fmaf(tx, wh[i * 16 + j], acch[j]);
            }
        }
    }
    float h2[16];
#pragma unroll
    for (int j = 0; j < 16; j++) {
        float az = accz[j] + bx2[j] + bh2[j];
        float ah = acch[j] + bx2[32 + j] + bh2[32 + j];
        float z = 1.f / (1.f + __expf(-az));
        float t = __expf(-2.f * fabsf(ah));
        float ht = copysignf((1.f - t) / (1.f + t), ah);
        float v = (1.f - z) * ht;
        h2[j] = fmaxf(v, 0.f);
    }
#pragma unroll
    for (int p = 0; p < 12; p++) {
        float o = bl[p];
#pragma unroll
        for (int j = 0; j < 16; j++) o = fmaf(h2[j], Wl[p * 16 + j], o);
        out[n * 12 + p] = o;
    }
}

// ---------------- launch ----------------

extern "C" void kernel_launch(void* const* d_in, const int* in_sizes, int n_in,
                              void* d_out, int out_size, void* d_ws, size_t ws_size,
                              hipStream_t stream) {
    const float* x   = (const float*)d_in[0];
    const int*   ei  = (const int*)d_in[1];
    const float* ew  = (const float*)d_in[2];
    const float* Wx1 = (const float*)d_in[3];
    const float* bx1 = (const float*)d_in[4];
    const float* bh1 = (const float*)d_in[6];
    const float* Wx2 = (const float*)d_in[7];
    const float* bx2 = (const float*)d_in[8];
    const float* bh2 = (const float*)d_in[10];
    const float* Wl  = (const float*)d_in[11];
    const float* bl  = (const float*)d_in[12];
    float* out = (float*)d_out;

    float* ws  = (float*)d_ws;
    float* deg = ws;                       // NN floats (becomes dis in-place)
    int*   cnt = (int*)(ws + 50048);       // NN ints (becomes cursor)
    int*   off = cnt + 50048;              // NN+1 ints
    int2*  edges = (int2*)(off + 50064);   // NE int2 (row, weight-bits)
    float* T1  = (float*)(edges + NE);     // NN*32 floats each
    float* T2  = T1 + NN * 32;
    float* T3  = T2 + NN * 32;
    float* T4  = T3 + NN * 32;
    float* hb  = T4 + NN * 32;

    const int gE = (NE + 255) / 256;
    const int gN = (NN + 255) / 256;
    const int gG = (NN * 8 + 255) / 256;

    // deg and cnt are adjacent: one memset covers both
    hipMemsetAsync(deg, 0, (50048 + 50048) * sizeof(float), stream);
    k_deg<<<gE, 256, 0, stream>>>(ei, ew, deg);
    k_dis<<<gN, 256, 0, stream>>>(deg);
    k_hist<<<gE, 256, 0, stream>>>(ei, cnt);
    k_scan<<<1, 1024, 0, stream>>>(cnt, off);
    k_permute<<<gE, 256, 0, stream>>>(ei, ew, deg, cnt, edges);

    // ---- cell 1: v = x ----
    k_gather<<<gG, 256, 0, stream>>>(off, edges, x,  nullptr, T1, 1.f);  // T1 = L x
    k_gather<<<gG, 256, 0, stream>>>(off, edges, T1, x,       T2, 2.f);  // T2 = 2 L T1 - x
    k_gather<<<gG, 256, 0, stream>>>(off, edges, T2, T1,      T3, 2.f);  // T3 = 2 L T2 - T1
    k_gather<<<gG, 256, 0, stream>>>(off, edges, T3, T2,      T4, 2.f);  // T4 = 2 L T3 - T2
    k_epi1<<<gN, 256, 0, stream>>>(x, T1, T2, T3, T4, Wx1, bx1, bh1, hb);

    // ---- cell 2: v = hb (reuse T buffers) ----
    k_gather<<<gG, 256, 0, stream>>>(off, edges, hb, nullptr, T1, 1.f);
    k_gather<<<gG, 256, 0, stream>>>(off, edges, T1, hb,      T2, 2.f);
    k_gather<<<gG, 256, 0, stream>>>(off, edges, T2, T1,      T3, 2.f);
    k_gather<<<gG, 256, 0, stream>>>(off, edges, T3, T2,      T4, 2.f);
    k_epi2<<<gN, 256, 0, stream>>>(hb, T1, T2, T3, T4, Wx2, bx2, bh2, Wl, bl, out);
}

// Round 3
// 729.321 us; speedup vs baseline: 7.5008x; 1.2276x over previous
//
#include <hip/hip_runtime.h>
#include <math.h>

#define NN 50000
#define NE 1600000
#define KORD 5
#define NB 196  // ceil(NN/256)

// ---------------- preprocessing ----------------

// fused: weighted out-degree (float) + destination histogram (int)
__global__ __launch_bounds__(256) void k_degh(const int* __restrict__ ei,
                                              const float* __restrict__ ew,
                                              float* __restrict__ deg,
                                              int* __restrict__ cnt) {
    int e = blockIdx.x * 256 + threadIdx.x;
    if (e < NE) {
        unsafeAtomicAdd(&deg[ei[e]], ew[e]);
        atomicAdd(&cnt[ei[NE + e]], 1);
    }
}

__global__ __launch_bounds__(256) void k_dis(float* __restrict__ deg) {
    int n = blockIdx.x * 256 + threadIdx.x;
    if (n < NN) {
        float d = deg[n];
        deg[n] = d > 0.f ? rsqrtf(fmaxf(d, 1e-30f)) : 0.f;
    }
}

// ---- hierarchical exclusive scan of cnt[NN] -> off[NN+1]; cnt becomes cursor

__global__ __launch_bounds__(256) void k_scan1(const int* __restrict__ cnt,
                                               int* __restrict__ bsum) {
    __shared__ int red[256];
    int idx = blockIdx.x * 256 + threadIdx.x;
    red[threadIdx.x] = idx < NN ? cnt[idx] : 0;
    __syncthreads();
    for (int d = 128; d > 0; d >>= 1) {
        if (threadIdx.x < d) red[threadIdx.x] += red[threadIdx.x + d];
        __syncthreads();
    }
    if (threadIdx.x == 0) bsum[blockIdx.x] = red[0];
}

// single block: exclusive-scan the NB block sums in place
__global__ __launch_bounds__(256) void k_scan2(int* __restrict__ bsum,
                                               int* __restrict__ off) {
    __shared__ int s[256];
    int t = threadIdx.x;
    int v = t < NB ? bsum[t] : 0;
    s[t] = v;
    __syncthreads();
    for (int d = 1; d < 256; d <<= 1) {
        int u = (t >= d) ? s[t - d] : 0;
        __syncthreads();
        s[t] += u;
        __syncthreads();
    }
    if (t < NB) bsum[t] = (t == 0) ? 0 : s[t - 1];
    if (t == 0) off[NN] = NE;  // total is statically known
}

__global__ __launch_bounds__(256) void k_scan3(int* __restrict__ cnt,
                                               const int* __restrict__ bsum,
                                               int* __restrict__ off) {
    __shared__ int s[256];
    int idx = blockIdx.x * 256 + threadIdx.x;
    int t = threadIdx.x;
    int v = idx < NN ? cnt[idx] : 0;
    s[t] = v;
    __syncthreads();
    for (int d = 1; d < 256; d <<= 1) {
        int u = (t >= d) ? s[t - d] : 0;
        __syncthreads();
        s[t] += u;
        __syncthreads();
    }
    if (idx < NN) {
        int excl = ((t == 0) ? 0 : s[t - 1]) + bsum[blockIdx.x];
        off[idx] = excl;
        cnt[idx] = excl;  // cursor for permute
    }
}

// bucket edges by destination; pack (row, weight) into int2
__global__ __launch_bounds__(256) void k_permute(const int* __restrict__ ei,
                                                 const float* __restrict__ ew,
                                                 const float* __restrict__ dis,
                                                 int* __restrict__ cursor,
                                                 int2* __restrict__ edges) {
    int e = blockIdx.x * 256 + threadIdx.x;
    if (e >= NE) return;
    int r = ei[e], c = ei[NE + e];
    float w = -dis[r] * ew[e] * dis[c];
    int pos = atomicAdd(&cursor[c], 1);
    edges[pos] = make_int2(r, __float_as_int(w));
}

// ---------------- spmm gather: vout[n] = scale * sum_e w_e * vin[r_e] - prev[n]
// 8 lanes per node, float4 (4 features) per lane; edge loop unrolled x4 for MLP.

__global__ __launch_bounds__(256) void k_gather(const int* __restrict__ off,
                                                const int2* __restrict__ edges,
                                                const float* __restrict__ vin,
                                                const float* __restrict__ prev,
                                                float* __restrict__ vout,
                                                float scale) {
    int t = blockIdx.x * 256 + threadIdx.x;
    if (t >= NN * 8) return;
    int n = t >> 3, sub = t & 7;
    const float4* vin4 = (const float4*)vin;
    float ax = 0.f, ay = 0.f, az = 0.f, aw = 0.f;
    int i = off[n], e1 = off[n + 1];
    for (; i + 4 <= e1; i += 4) {
        int2 ea = edges[i], eb = edges[i + 1], ec = edges[i + 2], ed = edges[i + 3];
        float4 va = vin4[ea.x * 8 + sub];
        float4 vb = vin4[eb.x * 8 + sub];
        float4 vc = vin4[ec.x * 8 + sub];
        float4 vd = vin4[ed.x * 8 + sub];
        float wa = __int_as_float(ea.y), wb = __int_as_float(eb.y);
        float wc = __int_as_float(ec.y), wd = __int_as_float(ed.y);
        ax = fmaf(wa, va.x, ax); ay = fmaf(wa, va.y, ay);
        az = fmaf(wa, va.z, az); aw = fmaf(wa, va.w, aw);
        ax = fmaf(wb, vb.x, ax); ay = fmaf(wb, vb.y, ay);
        az = fmaf(wb, vb.z, az); aw = fmaf(wb, vb.w, aw);
        ax = fmaf(wc, vc.x, ax); ay = fmaf(wc, vc.y, ay);
        az = fmaf(wc, vc.z, az); aw = fmaf(wc, vc.w, aw);
        ax = fmaf(wd, vd.x, ax); ay = fmaf(wd, vd.y, ay);
        az = fmaf(wd, vd.z, az); aw = fmaf(wd, vd.w, aw);
    }
    for (; i < e1; i++) {
        int2 er = edges[i];
        float w = __int_as_float(er.y);
        float4 v = vin4[er.x * 8 + sub];
        ax = fmaf(w, v.x, ax); ay = fmaf(w, v.y, ay);
        az = fmaf(w, v.z, az); aw = fmaf(w, v.w, aw);
    }
    float4 o;
    if (prev) {
        float4 p = ((const float4*)prev)[t];
        o = make_float4(fmaf(scale, ax, -p.x), fmaf(scale, ay, -p.y),
                        fmaf(scale, az, -p.z), fmaf(scale, aw, -p.w));
    } else {
        o = make_float4(ax, ay, az, aw);
    }
    ((float4*)vout)[t] = o;
}

// ---------------- fused gate GEMM + GRU nonlinearity, cell 1 ----------------
// H=0 => h = relu((1 - sigmoid(sum_k Txk@Wx1[0,k] + bx1[0] + bh1[0]))
//              * tanh(sum_k Txk@Wx1[2,k] + bx1[2] + bh1[2]))

__global__ __launch_bounds__(256) void k_epi1(
    const float* __restrict__ x, const float* __restrict__ t1,
    const float* __restrict__ t2, const float* __restrict__ t3,
    const float* __restrict__ t4, const float* __restrict__ Wx1,
    const float* __restrict__ bx1, const float* __restrict__ bh1,
    float* __restrict__ h) {
    int n = blockIdx.x * 256 + threadIdx.x;
    if (n >= NN) return;
    const float* tp[KORD] = {x + n * 32, t1 + n * 32, t2 + n * 32,
                             t3 + n * 32, t4 + n * 32};
    float accz[32], acch[32];
#pragma unroll
    for (int j = 0; j < 32; j++) { accz[j] = 0.f; acch[j] = 0.f; }
    const float* Wz = Wx1;                      // gate 0
    const float* Wh = Wx1 + 2 * KORD * 32 * 32; // gate 2
#pragma unroll
    for (int k = 0; k < KORD; k++) {
        const float* txp = tp[k];
        const float* wz = Wz + k * 32 * 32;
        const float* wh = Wh + k * 32 * 32;
        for (int i = 0; i < 32; i++) {
            float tx = txp[i];
#pragma unroll
            for (int j = 0; j < 32; j++) {
                accz[j] = fmaf(tx, wz[i * 32 + j], accz[j]);
                acch[j] = fmaf(tx, wh[i * 32 + j], acch[j]);
            }
        }
    }
#pragma unroll
    for (int j = 0; j < 32; j++) {
        float az = accz[j] + bx1[j] + bh1[j];
        float ah = acch[j] + bx1[64 + j] + bh1[64 + j];
        float z = 1.f / (1.f + __expf(-az));
        float t = __expf(-2.f * fabsf(ah));
        float ht = copysignf((1.f - t) / (1.f + t), ah);
        float v = (1.f - z) * ht;
        h[n * 32 + j] = fmaxf(v, 0.f);
    }
}

// ---------------- cell 2 epilogue fused with final linear ----------------

__global__ __launch_bounds__(256) void k_epi2(
    const float* __restrict__ h, const float* __restrict__ t1,
    const float* __restrict__ t2, const float* __restrict__ t3,
    const float* __restrict__ t4, const float* __restrict__ Wx2,
    const float* __restrict__ bx2, const float* __restrict__ bh2,
    const float* __restrict__ Wl, const float* __restrict__ bl,
    float* __restrict__ out) {
    int n = blockIdx.x * 256 + threadIdx.x;
    if (n >= NN) return;
    const float* tp[KORD] = {h + n * 32, t1 + n * 32, t2 + n * 32,
                             t3 + n * 32, t4 + n * 32};
    float accz[16], acch[16];
#pragma unroll
    for (int j = 0; j < 16; j++) { accz[j] = 0.f; acch[j] = 0.f; }
    const float* Wz = Wx2;                      // [K][32][16], gate 0
    const float* Wh = Wx2 + 2 * KORD * 32 * 16; // gate 2
#pragma unroll
    for (int k = 0; k < KORD; k++) {
        const float* txp = tp[k];
        const float* wz = Wz + k * 32 * 16;
        const float* wh = Wh + k * 32 * 16;
        for (int i = 0; i < 32; i++) {
            float tx = txp[i];
#pragma unroll
            for (int j = 0; j < 16; j++) {
                accz[j] = fmaf(tx, wz[i * 16 + j], accz[j]);
                acch[j] = fmaf(tx, wh[i * 16 + j], acch[j]);
            }
        }
    }
    float h2[16];
#pragma unroll
    for (int j = 0; j < 16; j++) {
        float az = accz[j] + bx2[j] + bh2[j];
        float ah = acch[j] + bx2[32 + j] + bh2[32 + j];
        float z = 1.f / (1.f + __expf(-az));
        float t = __expf(-2.f * fabsf(ah));
        float ht = copysignf((1.f - t) / (1.f + t), ah);
        float v = (1.f - z) * ht;
        h2[j] = fmaxf(v, 0.f);
    }
#pragma unroll
    for (int p = 0; p < 12; p++) {
        float o = bl[p];
#pragma unroll
        for (int j = 0; j < 16; j++) o = fmaf(h2[j], Wl[p * 16 + j], o);
        out[n * 12 + p] = o;
    }
}

// ---------------- launch ----------------

extern "C" void kernel_launch(void* const* d_in, const int* in_sizes, int n_in,
                              void* d_out, int out_size, void* d_ws, size_t ws_size,
                              hipStream_t stream) {
    const float* x   = (const float*)d_in[0];
    const int*   ei  = (const int*)d_in[1];
    const float* ew  = (const float*)d_in[2];
    const float* Wx1 = (const float*)d_in[3];
    const float* bx1 = (const float*)d_in[4];
    const float* bh1 = (const float*)d_in[6];
    const float* Wx2 = (const float*)d_in[7];
    const float* bx2 = (const float*)d_in[8];
    const float* bh2 = (const float*)d_in[10];
    const float* Wl  = (const float*)d_in[11];
    const float* bl  = (const float*)d_in[12];
    float* out = (float*)d_out;

    float* ws  = (float*)d_ws;
    float* deg = ws;                       // NN floats (becomes dis in-place)
    int*   cnt = (int*)(ws + 50048);       // NN ints (becomes cursor)
    int*   off = cnt + 50048;              // NN+1 ints
    int*   bsum = off + 50064;             // NB ints (pad to 256)
    int2*  edges = (int2*)(bsum + 256);    // NE int2 (row, weight-bits)
    float* T1  = (float*)(edges + NE);     // NN*32 floats each
    float* T2  = T1 + NN * 32;
    float* T3  = T2 + NN * 32;
    float* T4  = T3 + NN * 32;
    float* hb  = T4 + NN * 32;

    const int gE = (NE + 255) / 256;
    const int gN = (NN + 255) / 256;
    const int gG = (NN * 8 + 255) / 256;

    // deg and cnt are adjacent: one memset covers both
    hipMemsetAsync(deg, 0, (50048 + 50048) * sizeof(float), stream);
    k_degh<<<gE, 256, 0, stream>>>(ei, ew, deg, cnt);
    k_dis<<<gN, 256, 0, stream>>>(deg);
    k_scan1<<<NB, 256, 0, stream>>>(cnt, bsum);
    k_scan2<<<1, 256, 0, stream>>>(bsum, off);
    k_scan3<<<NB, 256, 0, stream>>>(cnt, bsum, off);
    k_permute<<<gE, 256, 0, stream>>>(ei, ew, deg, cnt, edges);

    // ---- cell 1: v = x ----
    k_gather<<<gG, 256, 0, stream>>>(off, edges, x,  nullptr, T1, 1.f);  // T1 = L x
    k_gather<<<gG, 256, 0, stream>>>(off, edges, T1, x,       T2, 2.f);  // T2 = 2 L T1 - x
    k_gather<<<gG, 256, 0, stream>>>(off, edges, T2, T1,      T3, 2.f);  // T3 = 2 L T2 - T1
    k_gather<<<gG, 256, 0, stream>>>(off, edges, T3, T2,      T4, 2.f);  // T4 = 2 L T3 - T2
    k_epi1<<<gN, 256, 0, stream>>>(x, T1, T2, T3, T4, Wx1, bx1, bh1, hb);

    // ---- cell 2: v = hb (reuse T buffers) ----
    k_gather<<<gG, 256, 0, stream>>>(off, edges, hb, nullptr, T1, 1.f);
    k_gather<<<gG, 256, 0, stream>>>(off, edges, T1, hb,      T2, 2.f);
    k_gather<<<gG, 256, 0, stream>>>(off, edges, T2, T1,      T3, 2.f);
    k_gather<<<gG, 256, 0, stream>>>(off, edges, T3, T2,      T4, 2.f);
    k_epi2<<<gN, 256, 0, stream>>>(hb, T1, T2, T3, T4, Wx2, bx2, bh2, Wl, bl, out);
}

// Round 4
// 593.241 us; speedup vs baseline: 9.2213x; 1.2294x over previous
//
#include <hip/hip_runtime.h>
#include <math.h>

#define NN 50000
#define NE 1600000
#define KORD 5
#define NB 196        // ceil(NN/256) for 256-thread node kernels
#define NCHUNK 64     // edge chunks
#define ECHUNK (NE / NCHUNK)   // 25000 edges per chunk
#define QTR 12500     // node quarter
#define HALF 25000    // node half

// ---------------- deg: LDS-privatized weighted row histogram ----------------
// 256 blocks: quarter q = blockIdx.x>>6, chunk = blockIdx.x&63.
__global__ __launch_bounds__(1024) void k_deg(const int* __restrict__ ei,
                                              const float* __restrict__ ew,
                                              float* __restrict__ deg_g) {
    __shared__ float h[QTR];   // 50 KB
    int q = blockIdx.x >> 6, ch = blockIdx.x & 63;
    for (int i = threadIdx.x; i < QTR; i += 1024) h[i] = 0.f;
    __syncthreads();
    int base = ch * ECHUNK, lo = q * QTR;
    for (int e = base + threadIdx.x; e < base + ECHUNK; e += 1024) {
        int li = ei[e] - lo;
        if ((unsigned)li < (unsigned)QTR) atomicAdd(&h[li], ew[e]);
    }
    __syncthreads();
    float* outp = deg_g + blockIdx.x * QTR;
    for (int i = threadIdx.x; i < QTR; i += 1024) outp[i] = h[i];
}

// reduce 64 copies per quarter -> dis = rsqrt(deg)
__global__ __launch_bounds__(256) void k_dis2(const float* __restrict__ deg_g,
                                              float* __restrict__ dis) {
    int n = blockIdx.x * 256 + threadIdx.x;
    if (n >= NN) return;
    int q = n / QTR, i = n % QTR;
    const float* p = deg_g + (q * 64) * QTR + i;
    float s = 0.f;
#pragma unroll
    for (int c = 0; c < 64; c++) s += p[c * QTR];
    dis[n] = s > 0.f ? rsqrtf(fmaxf(s, 1e-30f)) : 0.f;
}

// ---------------- cnt: LDS-privatized col histogram, packed 2x uint16 -------
// 128 blocks: half hh = blockIdx.x>>6, chunk = blockIdx.x&63.
__global__ __launch_bounds__(1024) void k_cnt(const int* __restrict__ ei,
                                              unsigned* __restrict__ cnt_g) {
    __shared__ unsigned h[QTR];  // 12500 words = counts for 25000 nodes, 50 KB
    int hh = blockIdx.x >> 6, ch = blockIdx.x & 63;
    for (int i = threadIdx.x; i < QTR; i += 1024) h[i] = 0u;
    __syncthreads();
    int base = ch * ECHUNK, lo = hh * HALF;
    const int* cols = ei + NE;
    for (int e = base + threadIdx.x; e < base + ECHUNK; e += 1024) {
        int c = cols[e] - lo;
        if ((unsigned)c < (unsigned)HALF)
            atomicAdd(&h[c >> 1], (c & 1) ? 0x10000u : 1u);
    }
    __syncthreads();
    unsigned* outp = cnt_g + blockIdx.x * QTR;
    for (int i = threadIdx.x; i < QTR; i += 1024) outp[i] = h[i];
}

// cross-block exclusive prefix (packed) + unpacked per-node totals
__global__ __launch_bounds__(256) void k_excl(const unsigned* __restrict__ cnt_g,
                                              unsigned* __restrict__ pre_g,
                                              int* __restrict__ cnt) {
    int t = blockIdx.x * 256 + threadIdx.x;
    if (t >= HALF) return;
    int hh = t / QTR, w = t % QTR;
    int base = hh * 64 * QTR + w;
    unsigned run = 0;
    for (int c = 0; c < 64; c++) {
        unsigned v = cnt_g[base + c * QTR];
        pre_g[base + c * QTR] = run;
        run += v;  // fields < 2^16, no carry
    }
    int n0 = hh * HALF + 2 * w;
    cnt[n0]     = (int)(run & 0xffffu);
    cnt[n0 + 1] = (int)(run >> 16);
}

// ---- hierarchical exclusive scan of cnt[NN] -> off[NN+1] ----

__global__ __launch_bounds__(256) void k_scan1(const int* __restrict__ cnt,
                                               int* __restrict__ bsum) {
    __shared__ int red[256];
    int idx = blockIdx.x * 256 + threadIdx.x;
    red[threadIdx.x] = idx < NN ? cnt[idx] : 0;
    __syncthreads();
    for (int d = 128; d > 0; d >>= 1) {
        if (threadIdx.x < d) red[threadIdx.x] += red[threadIdx.x + d];
        __syncthreads();
    }
    if (threadIdx.x == 0) bsum[blockIdx.x] = red[0];
}

__global__ __launch_bounds__(256) void k_scan2(int* __restrict__ bsum,
                                               int* __restrict__ off) {
    __shared__ int s[256];
    int t = threadIdx.x;
    int v = t < NB ? bsum[t] : 0;
    s[t] = v;
    __syncthreads();
    for (int d = 1; d < 256; d <<= 1) {
        int u = (t >= d) ? s[t - d] : 0;
        __syncthreads();
        s[t] += u;
        __syncthreads();
    }
    if (t < NB) bsum[t] = (t == 0) ? 0 : s[t - 1];
    if (t == 0) off[NN] = NE;
}

__global__ __launch_bounds__(256) void k_scan3(const int* __restrict__ cnt,
                                               const int* __restrict__ bsum,
                                               int* __restrict__ off) {
    __shared__ int s[256];
    int idx = blockIdx.x * 256 + threadIdx.x;
    int t = threadIdx.x;
    s[t] = idx < NN ? cnt[idx] : 0;
    __syncthreads();
    for (int d = 1; d < 256; d <<= 1) {
        int u = (t >= d) ? s[t - d] : 0;
        __syncthreads();
        s[t] += u;
        __syncthreads();
    }
    if (idx < NN) off[idx] = ((t == 0) ? 0 : s[t - 1]) + bsum[blockIdx.x];
}

// ---------------- atomic-free counting-sort permute ----------------
// 128 blocks, same (half, chunk) partition as k_cnt. LDS cursors replay
// the local histogram; slot = off[c] + pre[b][c] + local_rank (unique).
__global__ __launch_bounds__(1024) void k_perm(const int* __restrict__ ei,
                                               const float* __restrict__ ew,
                                               const float* __restrict__ dis,
                                               const int* __restrict__ off,
                                               const unsigned* __restrict__ pre_g,
                                               int2* __restrict__ edges) {
    __shared__ unsigned cur[QTR];  // packed cursors for this half's 25000 nodes
    int hh = blockIdx.x >> 6, ch = blockIdx.x & 63;
    for (int i = threadIdx.x; i < QTR; i += 1024) cur[i] = 0u;
    __syncthreads();
    int base = ch * ECHUNK, lo = hh * HALF;
    int pbase = blockIdx.x * QTR;  // == (hh*64+ch)*QTR, matches cnt_g layout
    const int* cols = ei + NE;
    for (int e = base + threadIdx.x; e < base + ECHUNK; e += 1024) {
        int c = cols[e];
        int cl = c - lo;
        if ((unsigned)cl >= (unsigned)HALF) continue;
        int r = ei[e];
        float w = -dis[r] * ew[e] * dis[c];
        unsigned old = atomicAdd(&cur[cl >> 1], (cl & 1) ? 0x10000u : 1u);
        unsigned rank = (cl & 1) ? (old >> 16) : (old & 0xffffu);
        unsigned prew = pre_g[pbase + (cl >> 1)];
        unsigned preb = (cl & 1) ? (prew >> 16) : (prew & 0xffffu);
        edges[off[c] + (int)preb + (int)rank] = make_int2(r, __float_as_int(w));
    }
}

// ---------------- spmm gather: wave per node ----------------
// 64 lanes = 8 edge-slots x 8 feature-subs. Coalesced edge stream, no
// degree divergence; shfl_xor reduce over slots.
__global__ __launch_bounds__(256) void k_gather(const int* __restrict__ off,
                                                const int2* __restrict__ edges,
                                                const float* __restrict__ vin,
                                                const float* __restrict__ prev,
                                                float* __restrict__ vout,
                                                float scale) {
    int n = (blockIdx.x * 256 + threadIdx.x) >> 6;
    if (n >= NN) return;
    int lane = threadIdx.x & 63;
    int eslot = lane >> 3, sub = lane & 7;
    const float4* vin4 = (const float4*)vin;
    int e0 = off[n], e1 = off[n + 1];
    float ax = 0.f, ay = 0.f, az = 0.f, aw = 0.f;
    int i = e0 + eslot;
    for (; i + 8 < e1; i += 16) {  // two independent chains in flight
        int2 ea = edges[i];
        int2 eb = edges[i + 8];
        float4 va = vin4[ea.x * 8 + sub];
        float4 vb = vin4[eb.x * 8 + sub];
        float wa = __int_as_float(ea.y), wb = __int_as_float(eb.y);
        ax = fmaf(wa, va.x, ax); ay = fmaf(wa, va.y, ay);
        az = fmaf(wa, va.z, az); aw = fmaf(wa, va.w, aw);
        ax = fmaf(wb, vb.x, ax); ay = fmaf(wb, vb.y, ay);
        az = fmaf(wb, vb.z, az); aw = fmaf(wb, vb.w, aw);
    }
    if (i < e1) {
        int2 ea = edges[i];
        float4 va = vin4[ea.x * 8 + sub];
        float wa = __int_as_float(ea.y);
        ax = fmaf(wa, va.x, ax); ay = fmaf(wa, va.y, ay);
        az = fmaf(wa, va.z, az); aw = fmaf(wa, va.w, aw);
    }
#pragma unroll
    for (int m = 8; m < 64; m <<= 1) {
        ax += __shfl_xor(ax, m);
        ay += __shfl_xor(ay, m);
        az += __shfl_xor(az, m);
        aw += __shfl_xor(aw, m);
    }
    if (eslot == 0) {
        int t = n * 8 + sub;
        float4 o;
        if (prev) {
            float4 p = ((const float4*)prev)[t];
            o = make_float4(fmaf(scale, ax, -p.x), fmaf(scale, ay, -p.y),
                            fmaf(scale, az, -p.z), fmaf(scale, aw, -p.w));
        } else {
            o = make_float4(ax, ay, az, aw);
        }
        ((float4*)vout)[t] = o;
    }
}

// ---------------- fused gate GEMM + GRU nonlinearity, cell 1 ----------------

__global__ __launch_bounds__(256) void k_epi1(
    const float* __restrict__ x, const float* __restrict__ t1,
    const float* __restrict__ t2, const float* __restrict__ t3,
    const float* __restrict__ t4, const float* __restrict__ Wx1,
    const float* __restrict__ bx1, const float* __restrict__ bh1,
    float* __restrict__ h) {
    int n = blockIdx.x * 256 + threadIdx.x;
    if (n >= NN) return;
    const float* tp[KORD] = {x + n * 32, t1 + n * 32, t2 + n * 32,
                             t3 + n * 32, t4 + n * 32};
    float accz[32], acch[32];
#pragma unroll
    for (int j = 0; j < 32; j++) { accz[j] = 0.f; acch[j] = 0.f; }
    const float* Wz = Wx1;                      // gate 0
    const float* Wh = Wx1 + 2 * KORD * 32 * 32; // gate 2
#pragma unroll
    for (int k = 0; k < KORD; k++) {
        const float* txp = tp[k];
        const float* wz = Wz + k * 32 * 32;
        const float* wh = Wh + k * 32 * 32;
        for (int i = 0; i < 32; i++) {
            float tx = txp[i];
#pragma unroll
            for (int j = 0; j < 32; j++) {
                accz[j] = fmaf(tx, wz[i * 32 + j], accz[j]);
                acch[j] = fmaf(tx, wh[i * 32 + j], acch[j]);
            }
        }
    }
#pragma unroll
    for (int j = 0; j < 32; j++) {
        float az = accz[j] + bx1[j] + bh1[j];
        float ah = acch[j] + bx1[64 + j] + bh1[64 + j];
        float z = 1.f / (1.f + __expf(-az));
        float t = __expf(-2.f * fabsf(ah));
        float ht = copysignf((1.f - t) / (1.f + t), ah);
        float v = (1.f - z) * ht;
        h[n * 32 + j] = fmaxf(v, 0.f);
    }
}

// ---------------- cell 2 epilogue fused with final linear ----------------

__global__ __launch_bounds__(256) void k_epi2(
    const float* __restrict__ h, const float* __restrict__ t1,
    const float* __restrict__ t2, const float* __restrict__ t3,
    const float* __restrict__ t4, const float* __restrict__ Wx2,
    const float* __restrict__ bx2, const float* __restrict__ bh2,
    const float* __restrict__ Wl, const float* __restrict__ bl,
    float* __restrict__ out) {
    int n = blockIdx.x * 256 + threadIdx.x;
    if (n >= NN) return;
    const float* tp[KORD] = {h + n * 32, t1 + n * 32, t2 + n * 32,
                             t3 + n * 32, t4 + n * 32};
    float accz[16], acch[16];
#pragma unroll
    for (int j = 0; j < 16; j++) { accz[j] = 0.f; acch[j] = 0.f; }
    const float* Wz = Wx2;                      // [K][32][16], gate 0
    const float* Wh = Wx2 + 2 * KORD * 32 * 16; // gate 2
#pragma unroll
    for (int k = 0; k < KORD; k++) {
        const float* txp = tp[k];
        const float* wz = Wz + k * 32 * 16;
        const float* wh = Wh + k * 32 * 16;
        for (int i = 0; i < 32; i++) {
            float tx = txp[i];
#pragma unroll
            for (int j = 0; j < 16; j++) {
                accz[j] = fmaf(tx, wz[i * 16 + j], accz[j]);
                acch[j] = fmaf(tx, wh[i * 16 + j], acch[j]);
            }
        }
    }
    float h2[16];
#pragma unroll
    for (int j = 0; j < 16; j++) {
        float az = accz[j] + bx2[j] + bh2[j];
        float ah = acch[j] + bx2[32 + j] + bh2[32 + j];
        float z = 1.f / (1.f + __expf(-az));
        float t = __expf(-2.f * fabsf(ah));
        float ht = copysignf((1.f - t) / (1.f + t), ah);
        float v = (1.f - z) * ht;
        h2[j] = fmaxf(v, 0.f);
    }
#pragma unroll
    for (int p = 0; p < 12; p++) {
        float o = bl[p];
#pragma unroll
        for (int j = 0; j < 16; j++) o = fmaf(h2[j], Wl[p * 16 + j], o);
        out[n * 12 + p] = o;
    }
}

// ---------------- launch ----------------

extern "C" void kernel_launch(void* const* d_in, const int* in_sizes, int n_in,
                              void* d_out, int out_size, void* d_ws, size_t ws_size,
                              hipStream_t stream) {
    const float* x   = (const float*)d_in[0];
    const int*   ei  = (const int*)d_in[1];
    const float* ew  = (const float*)d_in[2];
    const float* Wx1 = (const float*)d_in[3];
    const float* bx1 = (const float*)d_in[4];
    const float* bh1 = (const float*)d_in[6];
    const float* Wx2 = (const float*)d_in[7];
    const float* bx2 = (const float*)d_in[8];
    const float* bh2 = (const float*)d_in[10];
    const float* Wl  = (const float*)d_in[11];
    const float* bl  = (const float*)d_in[12];
    float* out = (float*)d_out;

    float* ws   = (float*)d_ws;
    float* dis  = ws;                       // NN floats
    int*   cnt  = (int*)(ws + 50048);       // NN ints
    int*   off  = cnt + 50048;              // NN+1 ints
    int*   bsum = off + 50064;              // 256 ints
    int2*  edges = (int2*)(bsum + 256);     // NE int2
    float* T1   = (float*)(edges + NE);     // NN*32 floats each
    float* T2   = T1 + NN * 32;
    float* T3   = T2 + NN * 32;
    float* T4   = T3 + NN * 32;
    float* hb   = T4 + NN * 32;
    // Aliases (dead before first gather write to the same region):
    float*    deg_g = T1;            // 256*QTR floats = 12.8 MB (T1+T2)
    unsigned* cnt_g = (unsigned*)T3; // 128*QTR words = 6.4 MB
    unsigned* pre_g = (unsigned*)T4; // 128*QTR words = 6.4 MB

    const int gN = NB;
    const int gG = NN * 64 / 256;  // 12500 blocks, exact

    k_deg <<<256, 1024, 0, stream>>>(ei, ew, deg_g);
    k_cnt <<<128, 1024, 0, stream>>>(ei, cnt_g);
    k_dis2<<<gN, 256, 0, stream>>>(deg_g, dis);
    k_excl<<<(HALF + 255) / 256, 256, 0, stream>>>(cnt_g, pre_g, cnt);
    k_scan1<<<NB, 256, 0, stream>>>(cnt, bsum);
    k_scan2<<<1, 256, 0, stream>>>(bsum, off);
    k_scan3<<<NB, 256, 0, stream>>>(cnt, bsum, off);
    k_perm<<<128, 1024, 0, stream>>>(ei, ew, dis, off, pre_g, edges);

    // ---- cell 1: v = x ----
    k_gather<<<gG, 256, 0, stream>>>(off, edges, x,  nullptr, T1, 1.f);
    k_gather<<<gG, 256, 0, stream>>>(off, edges, T1, x,       T2, 2.f);
    k_gather<<<gG, 256, 0, stream>>>(off, edges, T2, T1,      T3, 2.f);
    k_gather<<<gG, 256, 0, stream>>>(off, edges, T3, T2,      T4, 2.f);
    k_epi1<<<gN, 256, 0, stream>>>(x, T1, T2, T3, T4, Wx1, bx1, bh1, hb);

    // ---- cell 2: v = hb ----
    k_gather<<<gG, 256, 0, stream>>>(off, edges, hb, nullptr, T1, 1.f);
    k_gather<<<gG, 256, 0, stream>>>(off, edges, T1, hb,      T2, 2.f);
    k_gather<<<gG, 256, 0, stream>>>(off, edges, T2, T1,      T3, 2.f);
    k_gather<<<gG, 256, 0, stream>>>(off, edges, T3, T2,      T4, 2.f);
    k_epi2<<<gN, 256, 0, stream>>>(hb, T1, T2, T3, T4, Wx2, bx2, bh2, Wl, bl, out);
}

// Round 5
// 568.691 us; speedup vs baseline: 9.6194x; 1.0432x over previous
//
#include <hip/hip_runtime.h>
#include <math.h>

#define NN 50000
#define NE 1600000
#define KORD 5
#define NB 196        // ceil(NN/256) for 256-thread node kernels
#define NCHUNK 64     // edge chunks
#define ECHUNK (NE / NCHUNK)   // 25000 edges per chunk
#define QTR 12500     // node quarter
#define HALF 25000    // node half
#define MT 64         // epi node tile

// ---------------- deg: LDS-privatized weighted row histogram ----------------
__global__ __launch_bounds__(1024) void k_deg(const int* __restrict__ ei,
                                              const float* __restrict__ ew,
                                              float* __restrict__ deg_g) {
    __shared__ float h[QTR];   // 50 KB
    int q = blockIdx.x >> 6, ch = blockIdx.x & 63;
    for (int i = threadIdx.x; i < QTR; i += 1024) h[i] = 0.f;
    __syncthreads();
    int base = ch * ECHUNK, lo = q * QTR;
    for (int e = base + threadIdx.x; e < base + ECHUNK; e += 1024) {
        int li = ei[e] - lo;
        if ((unsigned)li < (unsigned)QTR) atomicAdd(&h[li], ew[e]);
    }
    __syncthreads();
    float* outp = deg_g + blockIdx.x * QTR;
    for (int i = threadIdx.x; i < QTR; i += 1024) outp[i] = h[i];
}

__global__ __launch_bounds__(256) void k_dis2(const float* __restrict__ deg_g,
                                              float* __restrict__ dis) {
    int n = blockIdx.x * 256 + threadIdx.x;
    if (n >= NN) return;
    int q = n / QTR, i = n % QTR;
    const float* p = deg_g + (q * 64) * QTR + i;
    float s = 0.f;
#pragma unroll
    for (int c = 0; c < 64; c++) s += p[c * QTR];
    dis[n] = s > 0.f ? rsqrtf(fmaxf(s, 1e-30f)) : 0.f;
}

// ---------------- cnt: LDS-privatized col histogram, packed 2x uint16 -------
__global__ __launch_bounds__(1024) void k_cnt(const int* __restrict__ ei,
                                              unsigned* __restrict__ cnt_g) {
    __shared__ unsigned h[QTR];
    int hh = blockIdx.x >> 6, ch = blockIdx.x & 63;
    for (int i = threadIdx.x; i < QTR; i += 1024) h[i] = 0u;
    __syncthreads();
    int base = ch * ECHUNK, lo = hh * HALF;
    const int* cols = ei + NE;
    for (int e = base + threadIdx.x; e < base + ECHUNK; e += 1024) {
        int c = cols[e] - lo;
        if ((unsigned)c < (unsigned)HALF)
            atomicAdd(&h[c >> 1], (c & 1) ? 0x10000u : 1u);
    }
    __syncthreads();
    unsigned* outp = cnt_g + blockIdx.x * QTR;
    for (int i = threadIdx.x; i < QTR; i += 1024) outp[i] = h[i];
}

__global__ __launch_bounds__(256) void k_excl(const unsigned* __restrict__ cnt_g,
                                              unsigned* __restrict__ pre_g,
                                              int* __restrict__ cnt) {
    int t = blockIdx.x * 256 + threadIdx.x;
    if (t >= HALF) return;
    int hh = t / QTR, w = t % QTR;
    int base = hh * 64 * QTR + w;
    unsigned run = 0;
    for (int c = 0; c < 64; c++) {
        unsigned v = cnt_g[base + c * QTR];
        pre_g[base + c * QTR] = run;
        run += v;
    }
    int n0 = hh * HALF + 2 * w;
    cnt[n0]     = (int)(run & 0xffffu);
    cnt[n0 + 1] = (int)(run >> 16);
}

// ---- hierarchical exclusive scan of cnt[NN] -> off[NN+1] ----

__global__ __launch_bounds__(256) void k_scan1(const int* __restrict__ cnt,
                                               int* __restrict__ bsum) {
    __shared__ int red[256];
    int idx = blockIdx.x * 256 + threadIdx.x;
    red[threadIdx.x] = idx < NN ? cnt[idx] : 0;
    __syncthreads();
    for (int d = 128; d > 0; d >>= 1) {
        if (threadIdx.x < d) red[threadIdx.x] += red[threadIdx.x + d];
        __syncthreads();
    }
    if (threadIdx.x == 0) bsum[blockIdx.x] = red[0];
}

__global__ __launch_bounds__(256) void k_scan2(int* __restrict__ bsum,
                                               int* __restrict__ off) {
    __shared__ int s[256];
    int t = threadIdx.x;
    int v = t < NB ? bsum[t] : 0;
    s[t] = v;
    __syncthreads();
    for (int d = 1; d < 256; d <<= 1) {
        int u = (t >= d) ? s[t - d] : 0;
        __syncthreads();
        s[t] += u;
        __syncthreads();
    }
    if (t < NB) bsum[t] = (t == 0) ? 0 : s[t - 1];
    if (t == 0) off[NN] = NE;
}

__global__ __launch_bounds__(256) void k_scan3(const int* __restrict__ cnt,
                                               const int* __restrict__ bsum,
                                               int* __restrict__ off) {
    __shared__ int s[256];
    int idx = blockIdx.x * 256 + threadIdx.x;
    int t = threadIdx.x;
    s[t] = idx < NN ? cnt[idx] : 0;
    __syncthreads();
    for (int d = 1; d < 256; d <<= 1) {
        int u = (t >= d) ? s[t - d] : 0;
        __syncthreads();
        s[t] += u;
        __syncthreads();
    }
    if (idx < NN) off[idx] = ((t == 0) ? 0 : s[t - 1]) + bsum[blockIdx.x];
}

// ---------------- atomic-free counting-sort permute ----------------
__global__ __launch_bounds__(1024) void k_perm(const int* __restrict__ ei,
                                               const float* __restrict__ ew,
                                               const float* __restrict__ dis,
                                               const int* __restrict__ off,
                                               const unsigned* __restrict__ pre_g,
                                               int2* __restrict__ edges) {
    __shared__ unsigned cur[QTR];
    int hh = blockIdx.x >> 6, ch = blockIdx.x & 63;
    for (int i = threadIdx.x; i < QTR; i += 1024) cur[i] = 0u;
    __syncthreads();
    int base = ch * ECHUNK, lo = hh * HALF;
    int pbase = blockIdx.x * QTR;
    const int* cols = ei + NE;
    for (int e = base + threadIdx.x; e < base + ECHUNK; e += 1024) {
        int c = cols[e];
        int cl = c - lo;
        if ((unsigned)cl >= (unsigned)HALF) continue;
        int r = ei[e];
        float w = -dis[r] * ew[e] * dis[c];
        unsigned old = atomicAdd(&cur[cl >> 1], (cl & 1) ? 0x10000u : 1u);
        unsigned rank = (cl & 1) ? (old >> 16) : (old & 0xffffu);
        unsigned prew = pre_g[pbase + (cl >> 1)];
        unsigned preb = (cl & 1) ? (prew >> 16) : (prew & 0xffffu);
        edges[off[c] + (int)preb + (int)rank] = make_int2(r, __float_as_int(w));
    }
}

// ---------------- spmm gather: wave per node, 4 load chains ----------------
__global__ __launch_bounds__(256) void k_gather(const int* __restrict__ off,
                                                const int2* __restrict__ edges,
                                                const float* __restrict__ vin,
                                                const float* __restrict__ prev,
                                                float* __restrict__ vout,
                                                float scale) {
    int n = (blockIdx.x * 256 + threadIdx.x) >> 6;
    if (n >= NN) return;
    int lane = threadIdx.x & 63;
    int eslot = lane >> 3, sub = lane & 7;
    const float4* vin4 = (const float4*)vin;
    int e0 = off[n], e1 = off[n + 1];
    float ax = 0.f, ay = 0.f, az = 0.f, aw = 0.f;
    int i = e0 + eslot;
    for (; i + 24 < e1; i += 32) {  // four independent chains in flight
        int2 ea = edges[i];
        int2 eb = edges[i + 8];
        int2 ec = edges[i + 16];
        int2 ed = edges[i + 24];
        float4 va = vin4[ea.x * 8 + sub];
        float4 vb = vin4[eb.x * 8 + sub];
        float4 vc = vin4[ec.x * 8 + sub];
        float4 vd = vin4[ed.x * 8 + sub];
        float wa = __int_as_float(ea.y), wb = __int_as_float(eb.y);
        float wc = __int_as_float(ec.y), wd = __int_as_float(ed.y);
        ax = fmaf(wa, va.x, ax); ay = fmaf(wa, va.y, ay);
        az = fmaf(wa, va.z, az); aw = fmaf(wa, va.w, aw);
        ax = fmaf(wb, vb.x, ax); ay = fmaf(wb, vb.y, ay);
        az = fmaf(wb, vb.z, az); aw = fmaf(wb, vb.w, aw);
        ax = fmaf(wc, vc.x, ax); ay = fmaf(wc, vc.y, ay);
        az = fmaf(wc, vc.z, az); aw = fmaf(wc, vc.w, aw);
        ax = fmaf(wd, vd.x, ax); ay = fmaf(wd, vd.y, ay);
        az = fmaf(wd, vd.z, az); aw = fmaf(wd, vd.w, aw);
    }
    for (; i < e1; i += 8) {
        int2 ea = edges[i];
        float4 va = vin4[ea.x * 8 + sub];
        float wa = __int_as_float(ea.y);
        ax = fmaf(wa, va.x, ax); ay = fmaf(wa, va.y, ay);
        az = fmaf(wa, va.z, az); aw = fmaf(wa, va.w, aw);
    }
#pragma unroll
    for (int m = 8; m < 64; m <<= 1) {
        ax += __shfl_xor(ax, m);
        ay += __shfl_xor(ay, m);
        az += __shfl_xor(az, m);
        aw += __shfl_xor(aw, m);
    }
    if (eslot == 0) {
        int t = n * 8 + sub;
        float4 o;
        if (prev) {
            float4 p = ((const float4*)prev)[t];
            o = make_float4(fmaf(scale, ax, -p.x), fmaf(scale, ay, -p.y),
                            fmaf(scale, az, -p.z), fmaf(scale, aw, -p.w));
        } else {
            o = make_float4(ax, ay, az, aw);
        }
        ((float4*)vout)[t] = o;
    }
}

// ---------------- epi1: LDS-tiled GEMM (K=160 -> 32z+32h) + GRU fuse --------
// thread = (nq in 16, oq in 16): 4 nodes (stride 16) x 2 z-cols + 2 h-cols.
__global__ __launch_bounds__(256) void k_epi1(
    const float* __restrict__ x, const float* __restrict__ t1,
    const float* __restrict__ t2, const float* __restrict__ t3,
    const float* __restrict__ t4, const float* __restrict__ Wx1,
    const float* __restrict__ bx1, const float* __restrict__ bh1,
    float* __restrict__ h) {
    __shared__ float T[5][MT][33];  // 42.2 KB, pad 33 -> conflict-free cols
    int n0 = blockIdx.x * MT;
    const float* bufs[5] = {x, t1, t2, t3, t4};
#pragma unroll
    for (int b = 0; b < 5; b++) {
        for (int idx = threadIdx.x; idx < MT * 8; idx += 256) {
            int r = idx >> 3, c4 = idx & 7;
            int rr = n0 + r; if (rr >= NN) rr = NN - 1;  // clamp tail reads
            float4 v = *(const float4*)(bufs[b] + rr * 32 + c4 * 4);
            float* dst = &T[b][r][c4 * 4];
            dst[0] = v.x; dst[1] = v.y; dst[2] = v.z; dst[3] = v.w;
        }
    }
    __syncthreads();
    int nq = threadIdx.x & 15, oq = threadIdx.x >> 4;
    int ob = oq * 2;
    const float* Wz = Wx1;                        // [K][32][32] gate 0
    const float* Wh = Wx1 + 2 * KORD * 32 * 32;   // gate 2
    float az_[4][2] = {{0.f}}, ah_[4][2] = {{0.f}};
#pragma unroll
    for (int b = 0; b < 5; b++) {
#pragma unroll 4
        for (int i = 0; i < 32; i++) {
            int kw = b * 1024 + i * 32 + ob;
            float wz0 = Wz[kw], wz1 = Wz[kw + 1];
            float wh0 = Wh[kw], wh1 = Wh[kw + 1];
#pragma unroll
            for (int a = 0; a < 4; a++) {
                float tx = T[b][nq + 16 * a][i];
                az_[a][0] = fmaf(tx, wz0, az_[a][0]);
                az_[a][1] = fmaf(tx, wz1, az_[a][1]);
                ah_[a][0] = fmaf(tx, wh0, ah_[a][0]);
                ah_[a][1] = fmaf(tx, wh1, ah_[a][1]);
            }
        }
    }
#pragma unroll
    for (int a = 0; a < 4; a++) {
        int n = n0 + nq + 16 * a;
        if (n < NN) {
#pragma unroll
            for (int c = 0; c < 2; c++) {
                int j = ob + c;
                float zz = az_[a][c] + bx1[j] + bh1[j];
                float hh = ah_[a][c] + bx1[64 + j] + bh1[64 + j];
                float z = 1.f / (1.f + __expf(-zz));
                float tt = __expf(-2.f * fabsf(hh));
                float ht = copysignf((1.f - tt) / (1.f + tt), hh);
                h[n * 32 + j] = fmaxf((1.f - z) * ht, 0.f);
            }
        }
    }
}

// ---------------- epi2: LDS-tiled GEMM (K=160 -> 16z+16h) + final linear ----
__global__ __launch_bounds__(256) void k_epi2(
    const float* __restrict__ hin, const float* __restrict__ t1,
    const float* __restrict__ t2, const float* __restrict__ t3,
    const float* __restrict__ t4, const float* __restrict__ Wx2,
    const float* __restrict__ bx2, const float* __restrict__ bh2,
    const float* __restrict__ Wl, const float* __restrict__ bl,
    float* __restrict__ out) {
    __shared__ float T[5][MT][33];
    __shared__ float H2[MT][17];
    int n0 = blockIdx.x * MT;
    const float* bufs[5] = {hin, t1, t2, t3, t4};
#pragma unroll
    for (int b = 0; b < 5; b++) {
        for (int idx = threadIdx.x; idx < MT * 8; idx += 256) {
            int r = idx >> 3, c4 = idx & 7;
            int rr = n0 + r; if (rr >= NN) rr = NN - 1;
            float4 v = *(const float4*)(bufs[b] + rr * 32 + c4 * 4);
            float* dst = &T[b][r][c4 * 4];
            dst[0] = v.x; dst[1] = v.y; dst[2] = v.z; dst[3] = v.w;
        }
    }
    __syncthreads();
    int nq = threadIdx.x & 15, j = threadIdx.x >> 4;  // j = output col 0..15
    const float* Wz = Wx2;                        // [K][32][16] gate 0
    const float* Wh = Wx2 + 2 * KORD * 32 * 16;   // gate 2
    float az_[4] = {0.f}, ah_[4] = {0.f};
#pragma unroll
    for (int b = 0; b < 5; b++) {
#pragma unroll 4
        for (int i = 0; i < 32; i++) {
            int kw = b * 512 + i * 16 + j;
            float wz0 = Wz[kw], wh0 = Wh[kw];
#pragma unroll
            for (int a = 0; a < 4; a++) {
                float tx = T[b][nq + 16 * a][i];
                az_[a] = fmaf(tx, wz0, az_[a]);
                ah_[a] = fmaf(tx, wh0, ah_[a]);
            }
        }
    }
#pragma unroll
    for (int a = 0; a < 4; a++) {
        float zz = az_[a] + bx2[j] + bh2[j];
        float hh = ah_[a] + bx2[32 + j] + bh2[32 + j];
        float z = 1.f / (1.f + __expf(-zz));
        float tt = __expf(-2.f * fabsf(hh));
        float ht = copysignf((1.f - tt) / (1.f + tt), hh);
        H2[nq + 16 * a][j] = fmaxf((1.f - z) * ht, 0.f);
    }
    __syncthreads();
    for (int idx = threadIdx.x; idx < MT * 12; idx += 256) {
        int n = idx / 12, p = idx % 12;
        int gn = n0 + n;
        if (gn < NN) {
            float o = bl[p];
#pragma unroll
            for (int jj = 0; jj < 16; jj++) o = fmaf(H2[n][jj], Wl[p * 16 + jj], o);
            out[gn * 12 + p] = o;
        }
    }
}

// ---------------- launch ----------------

extern "C" void kernel_launch(void* const* d_in, const int* in_sizes, int n_in,
                              void* d_out, int out_size, void* d_ws, size_t ws_size,
                              hipStream_t stream) {
    const float* x   = (const float*)d_in[0];
    const int*   ei  = (const int*)d_in[1];
    const float* ew  = (const float*)d_in[2];
    const float* Wx1 = (const float*)d_in[3];
    const float* bx1 = (const float*)d_in[4];
    const float* bh1 = (const float*)d_in[6];
    const float* Wx2 = (const float*)d_in[7];
    const float* bx2 = (const float*)d_in[8];
    const float* bh2 = (const float*)d_in[10];
    const float* Wl  = (const float*)d_in[11];
    const float* bl  = (const float*)d_in[12];
    float* out = (float*)d_out;

    float* ws   = (float*)d_ws;
    float* dis  = ws;                       // NN floats
    int*   cnt  = (int*)(ws + 50048);       // NN ints
    int*   off  = cnt + 50048;              // NN+1 ints
    int*   bsum = off + 50064;              // 256 ints
    int2*  edges = (int2*)(bsum + 256);     // NE int2
    float* T1   = (float*)(edges + NE);     // NN*32 floats each
    float* T2   = T1 + NN * 32;
    float* T3   = T2 + NN * 32;
    float* T4   = T3 + NN * 32;
    float* hb   = T4 + NN * 32;
    // Aliases (dead before first gather write to the same region):
    float*    deg_g = T1;            // 256*QTR floats (T1+T2)
    unsigned* cnt_g = (unsigned*)T3; // 128*QTR words
    unsigned* pre_g = (unsigned*)T4; // 128*QTR words

    const int gE1 = (NN + MT - 1) / MT;  // 782 epi blocks
    const int gG = NN * 64 / 256;        // 12500 gather blocks

    k_deg <<<256, 1024, 0, stream>>>(ei, ew, deg_g);
    k_cnt <<<128, 1024, 0, stream>>>(ei, cnt_g);
    k_dis2<<<NB, 256, 0, stream>>>(deg_g, dis);
    k_excl<<<(HALF + 255) / 256, 256, 0, stream>>>(cnt_g, pre_g, cnt);
    k_scan1<<<NB, 256, 0, stream>>>(cnt, bsum);
    k_scan2<<<1, 256, 0, stream>>>(bsum, off);
    k_scan3<<<NB, 256, 0, stream>>>(cnt, bsum, off);
    k_perm<<<128, 1024, 0, stream>>>(ei, ew, dis, off, pre_g, edges);

    // ---- cell 1: v = x ----
    k_gather<<<gG, 256, 0, stream>>>(off, edges, x,  nullptr, T1, 1.f);
    k_gather<<<gG, 256, 0, stream>>>(off, edges, T1, x,       T2, 2.f);
    k_gather<<<gG, 256, 0, stream>>>(off, edges, T2, T1,      T3, 2.f);
    k_gather<<<gG, 256, 0, stream>>>(off, edges, T3, T2,      T4, 2.f);
    k_epi1<<<gE1, 256, 0, stream>>>(x, T1, T2, T3, T4, Wx1, bx1, bh1, hb);

    // ---- cell 2: v = hb ----
    k_gather<<<gG, 256, 0, stream>>>(off, edges, hb, nullptr, T1, 1.f);
    k_gather<<<gG, 256, 0, stream>>>(off, edges, T1, hb,      T2, 2.f);
    k_gather<<<gG, 256, 0, stream>>>(off, edges, T2, T1,      T3, 2.f);
    k_gather<<<gG, 256, 0, stream>>>(off, edges, T3, T2,      T4, 2.f);
    k_epi2<<<gE1, 256, 0, stream>>>(hb, T1, T2, T3, T4, Wx2, bx2, bh2, Wl, bl, out);
}